// Round 24
// baseline (102.891 us; speedup 1.0000x reference)
//
#include <hip/hip_runtime.h>
#include <hip/hip_bf16.h>
#include <stdint.h>

// C = (B,16,16): diag (k,k)=sigmoid(x·Wd[k]+bd[k]); off (i,j)=-softplus(x·Wo[r]+bo[r])
// Permuted GEMM out[b][c], c=i*16+j. M=65536 N=256 K=1024, bf16 MFMA 16x16x32.
// R24: model discriminator. BM=128, 512 blocks x 512 thr (8 waves 2Mx4N).
// A staged via gload_lds in 2-STEP units (256B contiguous per row per inst;
// 32KB units, ring-2 = 64KB LDS -> 2 blocks/CU). B read DIRECTLY from the
// fragment-ordered L2-resident image into regs each step (no LDS staging).
// Swapped-operand MFMA (lane holds 4 consecutive out cols) + R22's direct
// float4 stores. Waits: even step vmcnt(4) (A unit stays in flight), odd step
// vmcnt(0) (A deadline). Port-byte model predicts ~112us; DRAM-granule model
// predicts ~85us.

typedef __bf16 bf16x8 __attribute__((ext_vector_type(8)));
typedef float f32x4 __attribute__((ext_vector_type(4)));

#define THREADS 512
#define BM 128
#define KSTEPS 32
#define WBYTES 524288              // 32 step-images x 16 KB (fragment order)

#define AUNIT 32768                // A unit: 128 rows x 256B (2 K-steps) fp32
#define SMEM_SZ 65536              // 2 units -> 2 blocks/CU

__device__ __forceinline__ unsigned bf_rtne(unsigned u) {
  return (u + 0x7fffu + ((u >> 16) & 1u)) >> 16;
}
__device__ __forceinline__ unsigned pack2(float lo, float hi) {
  return bf_rtne(__float_as_uint(lo)) | (bf_rtne(__float_as_uint(hi)) << 16);
}
// A-fragment pack: scalar casts -> compiler emits v_cvt_pk_bf16_f32 (RTNE)
__device__ __forceinline__ bf16x8 packfrag(const f32x4& a, const f32x4& b) {
  bf16x8 r;
  r[0] = (__bf16)a[0]; r[1] = (__bf16)a[1]; r[2] = (__bf16)a[2]; r[3] = (__bf16)a[3];
  r[4] = (__bf16)b[0]; r[5] = (__bf16)b[1]; r[6] = (__bf16)b[2]; r[7] = (__bf16)b[3];
  return r;
}
__device__ __forceinline__ void gload_lds16(const void* g, void* l) {
  __builtin_amdgcn_global_load_lds(
      (const __attribute__((address_space(1))) unsigned int*)g,
      (__attribute__((address_space(3))) unsigned int*)l, 16, 0, 0);
}

// W image, fragment order (R13/R15-verified): (c,k): ch=k>>5, q=(k>>3)&3, e=k&7
// byte = ch*16384 + q*4096 + c*16 + e*2 ; wave frag-load = 4 x 256B segments.
__global__ void prep_kernel(const float* __restrict__ Wd, const float* __restrict__ bd,
                            const float* __restrict__ Wo, const float* __restrict__ bo,
                            char* __restrict__ wbuf, float* __restrict__ bias) {
  const int c = blockIdx.x;    // 0..255 output col
  const int t = threadIdx.x;   // 0..255, 4 consecutive k each
  const int i = c >> 4, j = c & 15;
  const float* src;
  float b;
  if (i == j) { src = Wd + i * 1024; b = bd[i]; }
  else { int r = i * 15 + (j < i ? j : j - 1); src = Wo + r * 1024; b = bo[r]; }
  if (t == 0) bias[c] = b;
  const int kk = t * 4;
  const int ch = kk >> 5, q = (kk >> 3) & 3, e = kk & 7;
  float4 v = *reinterpret_cast<const float4*>(src + kk);
  uint2 h;
  h.x = pack2(v.x, v.y);
  h.y = pack2(v.z, v.w);
  *reinterpret_cast<uint2*>(wbuf + ch * 16384 + q * 4096 + c * 16 + e * 2) = h;
}

__global__ __launch_bounds__(THREADS, 4) void cap_main(
    const float* __restrict__ x, const char* __restrict__ wbuf,
    const float* __restrict__ bias, float* __restrict__ out) {
  __shared__ char smem[SMEM_SZ];

  const int tid = threadIdx.x;
  const int wid = tid >> 6;
  const int lane = tid & 63;
  const int l15 = lane & 15;
  const int l4 = lane >> 4;
  const int wm = wid >> 2;       // 0..1: rows wm*64..+63
  const int wn = wid & 3;        // 0..3: cols wn*64..+63

  const size_t blkRow = (size_t)blockIdx.x * BM;

  // ---- A staging map (4 insts/thread per 2-step unit; 256B/row contiguous) ----
  // inst i: row = i*32 + (tid>>4); col bytes (tid&15)*16 within the 256B window,
  // pre-swizzled by (row&15)<<4. dest = i*8192 + tid*16 (linear).
  const unsigned acol = (unsigned)(((tid & 15) * 16) ^ (((tid >> 4) & 15) << 4));
  const char* asrc[4];
  unsigned adst[4];
#pragma unroll
  for (int i = 0; i < 4; ++i) {
    const int row = i * 32 + (tid >> 4);
    asrc[i] = (const char*)(x + (blkRow + (size_t)row) * 1024) + acol;
    adst[i] = (unsigned)(i * 8192 + tid * 16);
  }

  // A-frag read swizzle
  const unsigned swA = (unsigned)(l15 << 4);
  // B-frag global base: + t*16384 + n*256
  const char* wb = wbuf + l4 * 4096 + (wn * 64 + l15) * 16;

  f32x4 acc[4][4];
#pragma unroll
  for (int m = 0; m < 4; ++m)
#pragma unroll
    for (int n = 0; n < 4; ++n) acc[m][n] = (f32x4){0.f, 0.f, 0.f, 0.f};

#define STAGE_A2(SU, SL)                                                       \
  {                                                                            \
    _Pragma("unroll") for (int i = 0; i < 4; ++i)                              \
        gload_lds16(asrc[i] + (SU) * 256, smem + (SL) + adst[i]);              \
  }

#define SUBSTEP(T, UNIT, P, VM)                                                \
  {                                                                            \
    /* B frags direct from L2 image */                                         \
    const char* wt = wb + (T) * 16384;                                         \
    bf16x8 bfr[4];                                                             \
    _Pragma("unroll") for (int n = 0; n < 4; ++n)                              \
        bfr[n] = *reinterpret_cast<const bf16x8*>(wt + n * 256);               \
    /* A frags from LDS unit, parity P */                                      \
    const char* Ac = smem + (UNIT) * AUNIT;                                    \
    bf16x8 af[4];                                                              \
    _Pragma("unroll") for (int m = 0; m < 4; ++m) {                            \
      const unsigned rb = (unsigned)((wm * 64 + m * 16 + l15) * 256);          \
      f32x4 u0 = *reinterpret_cast<const f32x4*>(                              \
          Ac + rb + (((P) * 128 + l4 * 32) ^ swA));                            \
      f32x4 u1 = *reinterpret_cast<const f32x4*>(                              \
          Ac + rb + (((P) * 128 + l4 * 32 + 16) ^ swA));                       \
      af[m] = packfrag(u0, u1);                                                \
    }                                                                          \
    _Pragma("unroll") for (int m = 0; m < 4; ++m)                              \
      _Pragma("unroll") for (int n = 0; n < 4; ++n)                            \
        acc[m][n] = __builtin_amdgcn_mfma_f32_16x16x32_bf16(                   \
            bfr[n], af[m], acc[m][n], 0, 0, 0);                                \
    asm volatile("s_waitcnt vmcnt(" #VM ")" ::: "memory");                     \
    asm volatile("s_waitcnt lgkmcnt(0)" ::: "memory");                         \
    __builtin_amdgcn_s_barrier();                                              \
  }

  // ---- prologue: unit 0 (steps 0,1); drain; barrier ----
  STAGE_A2(0, 0);
  asm volatile("s_waitcnt vmcnt(0)" ::: "memory");
  __builtin_amdgcn_s_barrier();

  for (int s = 0; s < KSTEPS / 2; ++s) {
    const int su = (s + 1 < KSTEPS / 2) ? s + 1 : KSTEPS / 2 - 1;
    const int cu = s & 1;
    // even sub-step: issue next unit's 4 staging insts, keep them in flight
    STAGE_A2(su, (cu ^ 1) * AUNIT);
    SUBSTEP(2 * s, cu, 0, 4);
    // odd sub-step: A(s+1) deadline -> drain
    SUBSTEP(2 * s + 1, cu, 1, 0);
  }
#undef STAGE_A2
#undef SUBSTEP

  // ---- epilogue (R22-verified): bias + activation + direct float4 stores ----
  // lane holds out[blkRow + wm*64 + m*16 + l15][wn*64 + n*16 + l4*4 + j]
#pragma unroll
  for (int n = 0; n < 4; ++n) {
    const int colb = wn * 64 + n * 16 + l4 * 4;
    const float4 bb = *reinterpret_cast<const float4*>(bias + colb);
    const bool d0 = ((colb + 0) % 17) == 0;
    const bool d1 = ((colb + 1) % 17) == 0;
    const bool d2 = ((colb + 2) % 17) == 0;
    const bool d3 = ((colb + 3) % 17) == 0;
#pragma unroll
    for (int m = 0; m < 4; ++m) {
      const size_t row = blkRow + (size_t)(wm * 64 + m * 16 + l15);
      float4 o;
#pragma unroll
      for (int j2 = 0; j2 < 4; ++j2) {
        float v = acc[m][n][j2] + (&bb.x)[j2];
        float e = __expf(-fabsf(v));
        float sig = (v >= 0.f) ? 1.f / (1.f + e) : e / (1.f + e);
        float sp = fmaxf(v, 0.f) + __logf(1.f + e);
        const bool diag = j2 == 0 ? d0 : j2 == 1 ? d1 : j2 == 2 ? d2 : d3;
        (&o.x)[j2] = diag ? sig : -sp;
      }
      *reinterpret_cast<float4*>(out + row * 256 + colb) = o;
    }
  }
}

extern "C" void kernel_launch(void* const* d_in, const int* in_sizes, int n_in,
                              void* d_out, int out_size, void* d_ws, size_t ws_size,
                              hipStream_t stream) {
  const float* x = (const float*)d_in[0];
  const float* Wd = (const float*)d_in[1];
  const float* bd = (const float*)d_in[2];
  const float* Wo = (const float*)d_in[3];
  const float* bo = (const float*)d_in[4];
  float* out = (float*)d_out;
  char* wbuf = (char*)d_ws;                  // 512 KiB weight image
  float* bias = (float*)(wbuf + WBYTES);     // 1 KiB bias

  prep_kernel<<<dim3(256), dim3(256), 0, stream>>>(Wd, bd, Wo, bo, wbuf, bias);
  cap_main<<<dim3(512), dim3(THREADS), 0, stream>>>(x, wbuf, bias, out);
}

// Round 25
// 98.884 us; speedup vs baseline: 1.0405x; 1.0405x over previous
//
#include <hip/hip_runtime.h>
#include <hip/hip_bf16.h>
#include <stdint.h>

// C = (B,16,16): diag (k,k)=sigmoid(x·Wd[k]+bd[k]); off (i,j)=-softplus(x·Wo[r]+bo[r])
// Permuted GEMM out[b][c], c=i*16+j. M=65536 N=256 K=1024, bf16 MFMA 16x16x32.
// R25 = R22 restored (session best: 98.5 us). Swapped-operand MFMA mfma(W,x):
// lane holds 4 consecutive out cols -> direct float4 stores, no transpose
// epilogue. BM=128, 512 blocks x 512 thr (8 waves 2Mx4N); A fp32 via gload_lds
// (3-slot ring, pre-swizzled source); B via gload_lds (2-slot ring); per step
// issue B(t+1), A(t+2), wait vmcnt(2) after MFMA (A(t+2) stays in flight
// across the raw barrier); cvt_pk pack. LDS 80KB, 2 blocks/CU.
// Final model: all structures converge to 335 MB / ~3.3 TB/s effective
// mixed-stream read service rate (x largely L3-resident; FETCH=133MB) ->
// ~95-100 us floor. MfmaUtil 8% (not compute-bound).

typedef __bf16 bf16x8 __attribute__((ext_vector_type(8)));
typedef float f32x4 __attribute__((ext_vector_type(4)));

#define THREADS 512
#define BM 128
#define KSTEPS 32
#define WIMG 16384                 // per-K-step B image: 256 cols x 32 k x 2B
#define WBYTES (WIMG * KSTEPS)     // 512 KiB

#define ASLOT 16384                // A slot: 128 rows x 32 k x 4B fp32 (swizzled)
#define BBASE 49152                // A slots @0,16K,32K ; B slots @48K,64K
#define BSLOT 16384
#define SMEM_SZ 81920              // 80 KiB -> 2 blocks/CU

__device__ __forceinline__ unsigned bf_rtne(unsigned u) {
  return (u + 0x7fffu + ((u >> 16) & 1u)) >> 16;
}
__device__ __forceinline__ unsigned pack2(float lo, float hi) {
  return bf_rtne(__float_as_uint(lo)) | (bf_rtne(__float_as_uint(hi)) << 16);
}
// A-fragment pack: scalar casts -> compiler emits v_cvt_pk_bf16_f32 (RTNE)
__device__ __forceinline__ bf16x8 packfrag(const f32x4& a, const f32x4& b) {
  bf16x8 r;
  r[0] = (__bf16)a[0]; r[1] = (__bf16)a[1]; r[2] = (__bf16)a[2]; r[3] = (__bf16)a[3];
  r[4] = (__bf16)b[0]; r[5] = (__bf16)b[1]; r[6] = (__bf16)b[2]; r[7] = (__bf16)b[3];
  return r;
}
__device__ __forceinline__ void gload_lds16(const void* g, void* l) {
  __builtin_amdgcn_global_load_lds(
      (const __attribute__((address_space(1))) unsigned int*)g,
      (__attribute__((address_space(3))) unsigned int*)l, 16, 0, 0);
}

// B image per K-step (R4/R12-verified): byte(c,k)=(c*64+k*2)^(((c>>1)&3)<<4)
__global__ void prep_kernel(const float* __restrict__ Wd, const float* __restrict__ bd,
                            const float* __restrict__ Wo, const float* __restrict__ bo,
                            char* __restrict__ wbuf, float* __restrict__ bias) {
  const int c = blockIdx.x;    // 0..255 output col
  const int t = threadIdx.x;   // 0..255, 4 consecutive k each
  const int i = c >> 4, j = c & 15;
  const float* src;
  float b;
  if (i == j) { src = Wd + i * 1024; b = bd[i]; }
  else { int r = i * 15 + (j < i ? j : j - 1); src = Wo + r * 1024; b = bo[r]; }
  if (t == 0) bias[c] = b;
  const int kk = t * 4;
  const int img = kk >> 5, k5 = kk & 31;
  float4 v = *reinterpret_cast<const float4*>(src + kk);
  uint2 h;
  h.x = pack2(v.x, v.y);
  h.y = pack2(v.z, v.w);
  const unsigned off = (unsigned)((c * 64 + k5 * 2) ^ (((c >> 1) & 3) << 4));
  *reinterpret_cast<uint2*>(wbuf + img * WIMG + off) = h;
}

__global__ __launch_bounds__(THREADS, 4) void cap_main(
    const float* __restrict__ x, const char* __restrict__ wbuf,
    const float* __restrict__ bias, float* __restrict__ out) {
  __shared__ char smem[SMEM_SZ];

  const int tid = threadIdx.x;
  const int wid = tid >> 6;
  const int lane = tid & 63;
  const int l15 = lane & 15;
  const int l4 = lane >> 4;
  const int wm = wid >> 2;       // 0..1: rows wm*64..+63
  const int wn = wid & 3;        // 0..3: cols wn*64..+63

  const size_t blkRow = (size_t)blockIdx.x * BM;

  // ---- A staging map (2 insts/thread; 512 thr x 16B x 2 = 16 KB slot) ----
  const unsigned acol = (unsigned)(((tid & 7) * 16) ^ (((tid >> 3) & 7) << 4));
  const char* asrc[2];
  unsigned adst[2];
#pragma unroll
  for (int i = 0; i < 2; ++i) {
    const int row = i * 64 + (tid >> 3);
    asrc[i] = (const char*)(x + (blkRow + (size_t)row) * 1024) + acol;
    adst[i] = (unsigned)(i * 8192 + tid * 16);
  }

  // ---- fragment read bases ----
  const unsigned swA = (unsigned)((l15 & 7) << 4);
  const unsigned bbase = (unsigned)(wn * 4096 + l15 * 64 +
                                    ((l4 * 16) ^ (((l15 >> 1) & 3) << 4)));

  f32x4 acc[4][4];
#pragma unroll
  for (int m = 0; m < 4; ++m)
#pragma unroll
    for (int n = 0; n < 4; ++n) acc[m][n] = (f32x4){0.f, 0.f, 0.f, 0.f};

#define STAGE_A(CH, SL)                                                        \
  {                                                                            \
    _Pragma("unroll") for (int i = 0; i < 2; ++i)                              \
        gload_lds16(asrc[i] + (CH) * 128, smem + (SL) + adst[i]);              \
  }
#define STAGE_B(CH, SL)                                                        \
  {                                                                            \
    const char* wsp = wbuf + (CH) * WIMG;                                      \
    _Pragma("unroll") for (int i = 0; i < 2; ++i)                              \
        gload_lds16(wsp + i * 8192 + tid * 16,                                 \
                    smem + BBASE + (SL) + i * 8192 + tid * 16);                \
  }

  // ---- prologue: A(0), B(0), A(1); vmcnt(2) retires A(0)+B(0) ----
  STAGE_A(0, 0);
  STAGE_B(0, 0);
  STAGE_A(1, ASLOT);
  asm volatile("s_waitcnt vmcnt(2)\n\ts_barrier" ::: "memory");

  unsigned aR = 0;          // A slot of step t (ring of 3)
  unsigned aI = 2 * ASLOT;  // A slot of step t+2
  unsigned bR = 0;          // B slot of step t (ring of 2)

  for (int t = 0; t < KSTEPS; ++t) {
    // issue B(t+1) first (retired this step), then A(t+2) (stays in flight)
    const int tb = (t + 1 < KSTEPS) ? t + 1 : KSTEPS - 1;
    STAGE_B(tb, bR ^ BSLOT);
    const int ta = (t + 2 < KSTEPS) ? t + 2 : KSTEPS - 1;
    STAGE_A(ta, aI);

    // fragments: A fp32 -> cvt_pk bf16; B bf16 direct
    const char* Ac = smem + aR;
    const char* Bc = smem + BBASE + bR;
    bf16x8 af[4], bfr[4];
#pragma unroll
    for (int m = 0; m < 4; ++m) {
      const unsigned rb = (unsigned)((wm * 64 + m * 16 + l15) * 128);
      f32x4 u0 = *reinterpret_cast<const f32x4*>(Ac + rb + ((l4 * 32) ^ swA));
      f32x4 u1 = *reinterpret_cast<const f32x4*>(Ac + rb + ((l4 * 32 + 16) ^ swA));
      af[m] = packfrag(u0, u1);
    }
#pragma unroll
    for (int n = 0; n < 4; ++n)
      bfr[n] = *reinterpret_cast<const bf16x8*>(Bc + bbase + n * 1024);

    // SWAPPED operands: D col(lane&15)=x-row, D row(l4*4+j)=W-col
#pragma unroll
    for (int m = 0; m < 4; ++m)
#pragma unroll
      for (int n = 0; n < 4; ++n)
        acc[m][n] = __builtin_amdgcn_mfma_f32_16x16x32_bf16(bfr[n], af[m], acc[m][n], 0, 0, 0);

    // counted wait: retires B(t+1)+A(t+1); A(t+2)'s 2 insts stay in flight
    asm volatile("s_waitcnt vmcnt(2)" ::: "memory");
    asm volatile("s_waitcnt lgkmcnt(0)" ::: "memory");
    __builtin_amdgcn_s_barrier();

    // rotate rings
    aR = (aR == 2 * ASLOT) ? 0u : aR + ASLOT;
    aI = (aI == 2 * ASLOT) ? 0u : aI + ASLOT;
    bR ^= BSLOT;
  }
#undef STAGE_A
#undef STAGE_B

  // ---- epilogue: bias + activation + DIRECT float4 stores (no LDS, no sync) ----
  // lane holds out[blkRow + wm*64 + m*16 + l15][wn*64 + n*16 + l4*4 + j], j=0..3
#pragma unroll
  for (int n = 0; n < 4; ++n) {
    const int colb = wn * 64 + n * 16 + l4 * 4;
    const float4 bb = *reinterpret_cast<const float4*>(bias + colb);
    const bool d0 = ((colb + 0) % 17) == 0;
    const bool d1 = ((colb + 1) % 17) == 0;
    const bool d2 = ((colb + 2) % 17) == 0;
    const bool d3 = ((colb + 3) % 17) == 0;
#pragma unroll
    for (int m = 0; m < 4; ++m) {
      const size_t row = blkRow + (size_t)(wm * 64 + m * 16 + l15);
      float4 o;
#pragma unroll
      for (int j2 = 0; j2 < 4; ++j2) {
        float v = acc[m][n][j2] + (&bb.x)[j2];
        float e = __expf(-fabsf(v));
        float sig = (v >= 0.f) ? 1.f / (1.f + e) : e / (1.f + e);
        float sp = fmaxf(v, 0.f) + __logf(1.f + e);
        const bool diag = j2 == 0 ? d0 : j2 == 1 ? d1 : j2 == 2 ? d2 : d3;
        (&o.x)[j2] = diag ? sig : -sp;
      }
      *reinterpret_cast<float4*>(out + row * 256 + colb) = o;
    }
  }
}

extern "C" void kernel_launch(void* const* d_in, const int* in_sizes, int n_in,
                              void* d_out, int out_size, void* d_ws, size_t ws_size,
                              hipStream_t stream) {
  const float* x = (const float*)d_in[0];
  const float* Wd = (const float*)d_in[1];
  const float* bd = (const float*)d_in[2];
  const float* Wo = (const float*)d_in[3];
  const float* bo = (const float*)d_in[4];
  float* out = (float*)d_out;
  char* wbuf = (char*)d_ws;                  // 512 KiB weight image
  float* bias = (float*)(wbuf + WBYTES);     // 1 KiB bias

  prep_kernel<<<dim3(256), dim3(256), 0, stream>>>(Wd, bd, Wo, bo, wbuf, bias);
  cap_main<<<dim3(512), dim3(THREADS), 0, stream>>>(x, wbuf, bias, out);
}